// Round 12
// baseline (1285.893 us; speedup 1.0000x reference)
//
#include <hip/hip_runtime.h>
#include <hip/hip_bf16.h>

#define BB   128
#define SS   256
#define DD   512
#define HH   1024
#define NCC  128
#define NCLS 129
#define G4   4096   // 4*HH, gate-interleaved: j = hcol*4 + gate (f,i,g,o)
#define NWG  256    // persistent grid size

typedef __attribute__((ext_vector_type(8)))  short  short8;
typedef __attribute__((ext_vector_type(16))) float  f32x16;

static __device__ __forceinline__ float sigm(float x)  { return 1.0f / (1.0f + __expf(-x)); }
static __device__ __forceinline__ float tanh_(float x) { return 1.0f - 2.0f / (__expf(2.0f * x) + 1.0f); }
static __device__ __forceinline__ unsigned short f2b(float v) {
    __hip_bfloat16 h = __float2bfloat16(v);
    return *reinterpret_cast<unsigned short*>(&h);
}
static __device__ __forceinline__ short8 ld16(const unsigned short* p) {
    return *reinterpret_cast<const short8*>(p);
}

// ---- L2-bypassing 16B load from rolling base (h is cross-XCD dynamic data)
#define LDAB(d, B, L) asm volatile("global_load_dwordx4 %0, %1, off offset:" L " sc0 sc1" \
                                   : "=v"(d) : "v"(B))
// 4 contiguous 1KB loads then advance base 4KB (13-bit offset limit)
#define LD4(A, I) do { \
    LDAB(A[(I)+0], p, "0"); LDAB(A[(I)+1], p, "1024"); \
    LDAB(A[(I)+2], p, "2048"); LDAB(A[(I)+3], p, "3072"); p += 4096; } while (0)
#define LD16(A) do { LD4(A,0); LD4(A,4); LD4(A,8); LD4(A,12); } while (0)

// ---- waitcnt with data-tie so MFMAs can't be scheduled before the wait
#define WAITA(N, A) asm volatile("s_waitcnt vmcnt(" N ")" : \
    "+v"(A[0]),"+v"(A[1]),"+v"(A[2]),"+v"(A[3]),"+v"(A[4]),"+v"(A[5]),"+v"(A[6]),"+v"(A[7]), \
    "+v"(A[8]),"+v"(A[9]),"+v"(A[10]),"+v"(A[11]),"+v"(A[12]),"+v"(A[13]),"+v"(A[14]),"+v"(A[15]))

#define MF16(A, KB) do { \
    acc0 = __builtin_amdgcn_mfma_f32_32x32x16_bf16(A[0],  breg[(KB)+0],  acc0, 0,0,0); \
    acc1 = __builtin_amdgcn_mfma_f32_32x32x16_bf16(A[1],  breg[(KB)+1],  acc1, 0,0,0); \
    acc0 = __builtin_amdgcn_mfma_f32_32x32x16_bf16(A[2],  breg[(KB)+2],  acc0, 0,0,0); \
    acc1 = __builtin_amdgcn_mfma_f32_32x32x16_bf16(A[3],  breg[(KB)+3],  acc1, 0,0,0); \
    acc0 = __builtin_amdgcn_mfma_f32_32x32x16_bf16(A[4],  breg[(KB)+4],  acc0, 0,0,0); \
    acc1 = __builtin_amdgcn_mfma_f32_32x32x16_bf16(A[5],  breg[(KB)+5],  acc1, 0,0,0); \
    acc0 = __builtin_amdgcn_mfma_f32_32x32x16_bf16(A[6],  breg[(KB)+6],  acc0, 0,0,0); \
    acc1 = __builtin_amdgcn_mfma_f32_32x32x16_bf16(A[7],  breg[(KB)+7],  acc1, 0,0,0); \
    acc0 = __builtin_amdgcn_mfma_f32_32x32x16_bf16(A[8],  breg[(KB)+8],  acc0, 0,0,0); \
    acc1 = __builtin_amdgcn_mfma_f32_32x32x16_bf16(A[9],  breg[(KB)+9],  acc1, 0,0,0); \
    acc0 = __builtin_amdgcn_mfma_f32_32x32x16_bf16(A[10], breg[(KB)+10], acc0, 0,0,0); \
    acc1 = __builtin_amdgcn_mfma_f32_32x32x16_bf16(A[11], breg[(KB)+11], acc1, 0,0,0); \
    acc0 = __builtin_amdgcn_mfma_f32_32x32x16_bf16(A[12], breg[(KB)+12], acc0, 0,0,0); \
    acc1 = __builtin_amdgcn_mfma_f32_32x32x16_bf16(A[13], breg[(KB)+13], acc1, 0,0,0); \
    acc0 = __builtin_amdgcn_mfma_f32_32x32x16_bf16(A[14], breg[(KB)+14], acc0, 0,0,0); \
    acc1 = __builtin_amdgcn_mfma_f32_32x32x16_bf16(A[15], breg[(KB)+15], acc1, 0,0,0); \
} while (0)

// 16 gathered proj loads (normal caching); issued BEFORE the poll (r7 lesson),
// completed by the poll's vmcnt(0).
#define PRLOAD(DSTA, CLSBUF) do { \
    _Pragma("unroll") \
    for (int r = 0; r < 16; r++) { \
        int row = (r & 3) + 8 * (r >> 2) + 4 * half; \
        const float* pa = proj + (size_t)CLSBUF[row] * G4 + jg; \
        asm volatile("global_load_dword %0, %1, off" : "=v"(DSTA[r]) \
                     : "v"((unsigned long long)pa)); \
    } \
} while (0)

// ---------------- single fused persistent kernel ----------------
// Phase A (preamble, striped over 256 WGs): hb0 zero + Wh->bf16 conv (16
//   jobs/WG) + proj (1 LDS-tiled job/WG); all producer stores sc0 sc1
//   (write-through L3). Per-wave arrival (+16/line over the 32 counter
//   lines), GLOBAL wide poll, then ONE agent acquire-fence -> all later
//   cached reads (breg/x/proj) refetch fresh from L3. (NOT r4's mistake:
//   r4 fenced every step; this is once, before anything hot is cached.)
// Phase B (scan): r10/r11 decoupled-wave loop, byte-identical except poll
//   targets shift by the preamble's 16 (tv=(s+2)<<4); last step stores
//   hf32 sc0 sc1, posts arrival, GLOBAL poll.
// Phase C (final): second acquire fence; WGs 0..127 compute batch wg's
//   projection + log_softmax inline.
__global__ __launch_bounds__(128, 1)
void k_all(const int* __restrict__ x, const float* __restrict__ emb,
           const float* __restrict__ Wfh, const float* __restrict__ Wih,
           const float* __restrict__ Wgh, const float* __restrict__ Woh,
           const float* __restrict__ Wfx, const float* __restrict__ Wix,
           const float* __restrict__ Wgx, const float* __restrict__ Wox,
           const float* __restrict__ bf_, const float* __restrict__ bi_,
           const float* __restrict__ bg_, const float* __restrict__ bo_,
           const float* __restrict__ Wph, const float* __restrict__ bp,
           unsigned short* __restrict__ WhT, float* __restrict__ proj,
           unsigned short* __restrict__ hb0, unsigned short* __restrict__ hb1,
           float* __restrict__ hf32, int* __restrict__ flags,
           float* __restrict__ out) {
    const int wg = blockIdx.x, tid = threadIdx.x;
    const int lane = tid & 63, wv = tid >> 6;
    const int l31 = lane & 31, half = lane >> 5;
    const int mg = wg & 3, ng = wg >> 2;
    const int m0 = mg * 32, n0 = ng * 64;
    const int jg = n0 + wv * 32 + l31;       // this lane's gate-col

    __shared__ float  tls[32][33];    // conv transpose tile
    __shared__ float4 wxs[128][16];   // proj Wx tile (32KB)
    __shared__ float  sg[32][68];     // sigmoided gates [row][gate-col]
    __shared__ int    clsW[2][2][32]; // per-wave double-buffered class ids
    __shared__ float  red[128];       // final softmax reduction

    // arrival lines (zeroed by the hipMemsetAsync before this kernel):
    // wave posts to line (mg*8 + (ng&7)); 16 waves/line/round.
    const unsigned long long ctrAddr =
        (unsigned long long)(flags + (size_t)(8192 + mg * 256 + (ng & 7) * 32));
    const unsigned long long pollAddr =      // group-local: lane l -> line l&7
        (unsigned long long)(flags + (size_t)(8192 + mg * 256 + (lane & 7) * 32));
    const unsigned long long gpollAddr =     // global: lane l -> group (l>>3)&3, line l&7
        (unsigned long long)(flags + (size_t)(8192 + ((lane >> 3) & 3) * 256 + (lane & 7) * 32));

    // ================= Phase A: preamble =================
    {   // A1: zero hb0 (sc0 sc1 so step-0 UC A-loads see zeros at L3)
        unsigned long long za =
            (unsigned long long)((char*)hb0 + ((size_t)wg * 128 + tid) * 8);
        unsigned long long z64 = 0;
        asm volatile("global_store_dwordx2 %0, %1, off sc0 sc1" :: "v"(za), "v"(z64) : "memory");
    }
    // A2: Wh -> bf16 transposed gate-interleaved, 16 jobs per WG
    for (int t = 0; t < 16; t++) {
        int b = wg * 16 + t;
        int bx = b & 31, by = (b >> 5) & 31, g = b >> 10;
        const float* W = (g == 0) ? Wfh : (g == 1) ? Wih : (g == 2) ? Wgh : Woh;
        int h0 = bx * 32, k0 = by * 32;
        int tx = tid & 31, ty = tid >> 5;          // ty 0..3
        for (int r = 0; r < 8; r++) {
            int k = ty + r * 4;
            tls[k][tx] = W[(size_t)(k0 + k) * HH + h0 + tx];
        }
        __syncthreads();
        for (int r = 0; r < 8; r++) {
            int hl = ty + r * 4;
            int j  = (h0 + hl) * 4 + g;
            int v  = (int)f2b(tls[tx][hl]);
            unsigned long long wa =
                (unsigned long long)(WhT + (size_t)j * HH + k0 + tx);
            asm volatile("global_store_short %0, %1, off sc0 sc1" :: "v"(wa), "v"(v) : "memory");
        }
        __syncthreads();
    }
    // A3: proj, exactly one (gate, 16-hcol) tile per WG (r11 algorithm)
    {
        int g = wg & 3, hcol0 = (wg >> 2) * 16;
        const float* Wx = (g == 0) ? Wfx : (g == 1) ? Wix : (g == 2) ? Wgx : Wox;
        const float* bb = (g == 0) ? bf_ : (g == 1) ? bi_ : (g == 2) ? bg_ : bo_;
        for (int i = tid; i < 2048; i += 128) {
            int d4 = i >> 4, hc = i & 15;
            const float* w = Wx + (size_t)(d4 * 4) * HH + hcol0 + hc;
            wxs[d4][hc] = make_float4(w[0], w[HH], w[2 * HH], w[3 * HH]);
        }
        __syncthreads();
        int hc = tid & 15, c0 = tid >> 4;          // c0 0..7
        float bias = bb[hcol0 + hc];
        for (int c = c0; c < NCLS; c += 8) {
            const float4* er = reinterpret_cast<const float4*>(emb + (size_t)c * DD);
            float acc = bias;
            #pragma unroll 8
            for (int d4 = 0; d4 < 128; d4++) {
                float4 e = er[d4];
                float4 w = wxs[d4][hc];
                acc += e.x * w.x + e.y * w.y + e.z * w.z + e.w * w.w;
            }
            unsigned long long pa = (unsigned long long)
                (proj + (size_t)c * G4 + (hcol0 + hc) * 4 + g);
            asm volatile("global_store_dword %0, %1, off sc0 sc1" :: "v"(pa), "v"(acc) : "memory");
        }
    }
    // A4: preamble global barrier (same machinery as the scan barrier)
    asm volatile("s_waitcnt vmcnt(0)" ::: "memory");
    __syncthreads();
    if (lane == 0) {
        int one = 1;
        asm volatile("global_atomic_add %0, %1, off" :: "v"(ctrAddr), "v"(one) : "memory");
    }
    {
        int got;
        do {
            asm volatile("global_load_dword %0, %1, off sc0 sc1\n\t"
                         "s_waitcnt vmcnt(0)"
                         : "=v"(got) : "v"(gpollAddr) : "memory");
        } while (__ballot(got >= 16) != ~0ull);
    }
    // A5: one-time invalidate so cached reads below see the preamble's writes
    __builtin_amdgcn_fence(__ATOMIC_ACQUIRE, "agent");

    // ================= Phase B: scan (r10/r11 winner) =================
    short8 breg[64];
    {
        const unsigned short* Bp = WhT + (size_t)jg * HH + half * 8;
        #pragma unroll
        for (int kk = 0; kk < 64; kk++) breg[kk] = ld16(Bp + kk * 16);
    }

    float Cst[4] = {0.0f, 0.0f, 0.0f, 0.0f};
    const int urow = tid & 31, uq = tid >> 5;   // uq in {2wv, 2wv+1}

    if (lane < 32) clsW[wv][0][lane] = x[(size_t)(m0 + lane) * SS];
    // no barrier: clsW[wv] is wave-private; lgkmcnt(0) below orders it

    const unsigned long long ab0 =
        (unsigned long long)((char*)hb0 + mg * 65536 + lane * 16);
    const unsigned long long ab1 =
        (unsigned long long)((char*)hb1 + mg * 65536 + lane * 16);
    const unsigned long long sb0 = (unsigned long long)((char*)hb0 + mg * 65536
        + ng * 1024 + (urow + ((uq >> 1) << 5)) * 16 + (uq & 1) * 8);
    const unsigned long long sb1 = (unsigned long long)((char*)hb1 + mg * 65536
        + ng * 1024 + (urow + ((uq >> 1) << 5)) * 16 + (uq & 1) * 8);

    float pr[16];
    PRLOAD(pr, clsW[wv][0]);        // step-0 proj gather (drained by first WAITA)

    for (int s = 0; s < SS; s++) {
        const int cur = s & 1;
        unsigned long long p = cur ? ab1 : ab0;
        const unsigned long long sb = cur ? sb0 : sb1;   // store to the OTHER buffer

        short8 a0[16], a1[16], a2[16], a3[16];
        LD16(a0);
        LD16(a1);

        f32x16 acc0, acc1;
        #pragma unroll
        for (int r = 0; r < 16; r++) { acc0[r] = 0.0f; acc1[r] = 0.0f; }

        WAITA("16", a0);
        LD16(a2);
        MF16(a0, 0);
        WAITA("16", a1);
        LD16(a3);
        MF16(a1, 16);
        WAITA("16", a2);
        MF16(a2, 32);
        WAITA("0", a3);
        MF16(a3, 48);

        // epilogue: add preloaded proj, sigmoid, stash in own sg cols
        #pragma unroll
        for (int r = 0; r < 16; r++) {
            int row = (r & 3) + 8 * (r >> 2) + 4 * half;
            sg[row][wv * 32 + l31] = sigm(acc0[r] + acc1[r] + pr[r]);
        }
        asm volatile("s_waitcnt lgkmcnt(0)" ::: "memory");

        // pointwise: thread owns (row = tid&31, hcols uq*4..+4)
        {
            const float rr = (clsW[wv][cur][urow] > 0) ? 1.0f : 0.0f;
            unsigned short hv[4];
            #pragma unroll
            for (int q = 0; q < 4; q++) {
                float4 gq = *reinterpret_cast<const float4*>(&sg[urow][uq * 16 + q * 4]);
                float cn = (gq.z * gq.y + Cst[q] * gq.x) * rr;   // (g*i + C*f)*r
                Cst[q] = cn;
                float hvv = gq.w * tanh_(cn);
                hv[q] = f2b(hvv);
                if (s == SS - 1) {
                    unsigned long long ha = (unsigned long long)
                        (hf32 + (size_t)(m0 + urow) * HH + ng * 16 + uq * 4 + q);
                    asm volatile("global_store_dword %0, %1, off sc0 sc1"
                                 :: "v"(ha), "v"(hvv) : "memory");
                }
            }
            unsigned long long pk = (unsigned long long)hv[0]
                                  | ((unsigned long long)hv[1] << 16)
                                  | ((unsigned long long)hv[2] << 32)
                                  | ((unsigned long long)hv[3] << 48);
            asm volatile("global_store_dwordx2 %0, %1, off sc0 sc1" :: "v"(sb), "v"(pk) : "memory");
            if (s + 1 < SS && lane < 32)
                clsW[wv][cur ^ 1][lane] = x[(size_t)(m0 + lane) * SS + s + 1];
        }

        // per-wave barrier leg (targets shifted +16 for the preamble round)
        if (s < SS - 1) {
            asm volatile("s_waitcnt vmcnt(0)" ::: "memory");
            if (lane == 0) {
                int one = 1;
                asm volatile("global_atomic_add %0, %1, off"
                             :: "v"(ctrAddr), "v"(one) : "memory");
            }
            PRLOAD(pr, clsW[wv][cur ^ 1]);
            const int tv = (s + 2) << 4;
            int got;
            do {
                asm volatile("global_load_dword %0, %1, off sc0 sc1\n\t"
                             "s_waitcnt vmcnt(0)"
                             : "=v"(got) : "v"(pollAddr) : "memory");
            } while (__ballot(got >= tv) != ~0ull);
        }
    }

    // last-step GLOBAL barrier: hf32 fully published before the final phase
    asm volatile("s_waitcnt vmcnt(0)" ::: "memory");
    if (lane == 0) {
        int one = 1;
        asm volatile("global_atomic_add %0, %1, off" :: "v"(ctrAddr), "v"(one) : "memory");
    }
    {
        const int tv = (SS + 1) << 4;   // 4112
        int got;
        do {
            asm volatile("global_load_dword %0, %1, off sc0 sc1\n\t"
                         "s_waitcnt vmcnt(0)"
                         : "=v"(got) : "v"(gpollAddr) : "memory");
        } while (__ballot(got >= tv) != ~0ull);
    }
    __builtin_amdgcn_fence(__ATOMIC_ACQUIRE, "agent");

    // ================= Phase C: final projection + log_softmax =================
    if (wg < BB) {
        const int b = wg, c = tid;
        const float* hr = hf32 + (size_t)b * HH;
        const float* wp = Wph + c;
        float acc = bp[c];
        const float4* h4 = reinterpret_cast<const float4*>(hr);
        #pragma unroll 8
        for (int k4 = 0; k4 < 256; k4++) {
            float4 h = h4[k4];
            const float* w = wp + (size_t)(k4 * 4) * NCC;
            acc += h.x * w[0] + h.y * w[NCC] + h.z * w[2 * NCC] + h.w * w[3 * NCC];
        }
        red[c] = acc;
        __syncthreads();
        for (int st = 64; st > 0; st >>= 1) {
            if (c < st) red[c] = fmaxf(red[c], red[c + st]);
            __syncthreads();
        }
        float m = red[0];
        __syncthreads();
        red[c] = __expf(acc - m);
        __syncthreads();
        for (int st = 64; st > 0; st >>= 1) {
            if (c < st) red[c] += red[c + st];
            __syncthreads();
        }
        out[(size_t)b * NCC + c] = acc - m - __logf(red[0]);
    }
}

extern "C" void kernel_launch(void* const* d_in, const int* in_sizes, int n_in,
                              void* d_out, int out_size, void* d_ws, size_t ws_size,
                              hipStream_t stream) {
    const int*   x   = (const int*)  d_in[0];
    const float* emb = (const float*)d_in[1];
    const float* Wfx = (const float*)d_in[2];
    const float* Wfh = (const float*)d_in[3];
    const float* bf_ = (const float*)d_in[4];
    const float* Wix = (const float*)d_in[5];
    const float* Wih = (const float*)d_in[6];
    const float* bi_ = (const float*)d_in[7];
    const float* Wgx = (const float*)d_in[8];
    const float* Wgh = (const float*)d_in[9];
    const float* bg_ = (const float*)d_in[10];
    const float* Wox = (const float*)d_in[11];
    const float* Woh = (const float*)d_in[12];
    const float* bo_ = (const float*)d_in[13];
    const float* Wph = (const float*)d_in[14];
    const float* bp_ = (const float*)d_in[15];
    float* out = (float*)d_out;

    char* ws = (char*)d_ws;
    unsigned short* WhT   = (unsigned short*)(ws);              // 8 MB
    float*          proj  = (float*)(ws + 8388608);             // 2.02 MB -> ends 10502144
    int*            flags = (int*)(ws + 10502656);              // 64 KB (16384 ints)
    unsigned short* hb0   = (unsigned short*)(ws + 10568192);   // 256 KB
    unsigned short* hb1   = (unsigned short*)(ws + 10830336);   // 256 KB
    float*          hf32  = (float*)(ws + 11092480);            // 512 KB -> ends ~11.6 MB

    hipMemsetAsync(flags, 0, 16384 * sizeof(int), stream);
    k_all<<<dim3(NWG), dim3(128), 0, stream>>>(
        x, emb, Wfh, Wih, Wgh, Woh, Wfx, Wix, Wgx, Wox,
        bf_, bi_, bg_, bo_, Wph, bp_,
        WhT, proj, hb0, hb1, hf32, flags, out);
}

// Round 13
// 1279.678 us; speedup vs baseline: 1.0049x; 1.0049x over previous
//
#include <hip/hip_runtime.h>
#include <hip/hip_bf16.h>

#define BB   128
#define SS   256
#define DD   512
#define HH   1024
#define NCC  128
#define NCLS 129
#define G4   4096   // 4*HH, gate-interleaved: j = hcol*4 + gate (f,i,g,o)
#define NWG  256    // persistent grid size

typedef __attribute__((ext_vector_type(8)))  short  short8;
typedef __attribute__((ext_vector_type(16))) float  f32x16;

static __device__ __forceinline__ float sigm(float x)  { return 1.0f / (1.0f + __expf(-x)); }
static __device__ __forceinline__ float tanh_(float x) { return 1.0f - 2.0f / (__expf(2.0f * x) + 1.0f); }
static __device__ __forceinline__ unsigned short f2b(float v) {
    __hip_bfloat16 h = __float2bfloat16(v);
    return *reinterpret_cast<unsigned short*>(&h);
}
static __device__ __forceinline__ short8 ld16(const unsigned short* p) {
    return *reinterpret_cast<const short8*>(p);
}

// ---------------- fused preamble: init + Wh-conv + proj (independent jobs) ----
// blocks [0,512)      : zero-init h buffer 0 and flag/counter block
// blocks [512,4608)   : Wh -> bf16, transposed, gate-interleaved
// blocks [4608,4864)  : proj, CLASS-TILED: block = (gate, 16-hcol tile), all
//   129 classes. Wx tile staged once in LDS (32KB) -> Wx read ONCE total
//   (8MB) instead of once per class (1GB); emb rows are float4 broadcasts.
__global__ void k_pre(unsigned short* __restrict__ hb0, int* __restrict__ flags,
                      const float* __restrict__ Wfh, const float* __restrict__ Wih,
                      const float* __restrict__ Wgh, const float* __restrict__ Woh,
                      unsigned short* __restrict__ WhT,
                      const float* __restrict__ emb,
                      const float* __restrict__ Wfx, const float* __restrict__ Wix,
                      const float* __restrict__ Wgx, const float* __restrict__ Wox,
                      const float* __restrict__ bf_, const float* __restrict__ bi_,
                      const float* __restrict__ bg_, const float* __restrict__ bo_,
                      float* __restrict__ proj) {
    __shared__ float  t[32][33];
    __shared__ float4 wxs[128][16];   // [d/4][hcol] tile of Wx, 32KB
    const int bid = blockIdx.x;
    if (bid < 512) {
        int i = bid * 256 + threadIdx.x;
        if (i < BB * HH) hb0[i] = 0;
        if (i < 16384) flags[i] = 0;
        return;
    }
    if (bid < 4608) {
        int b = bid - 512;
        int bx = b & 31, by = (b >> 5) & 31, g = b >> 10;
        const float* W = (g == 0) ? Wfh : (g == 1) ? Wih : (g == 2) ? Wgh : Woh;
        int h0 = bx * 32, k0 = by * 32;
        int tx = threadIdx.x & 31, ty = threadIdx.x >> 5;
        for (int r = 0; r < 4; r++) {
            int k = ty + r * 8;
            t[k][tx] = W[(size_t)(k0 + k) * HH + h0 + tx];
        }
        __syncthreads();
        for (int r = 0; r < 4; r++) {
            int hl = ty + r * 8;
            int j  = (h0 + hl) * 4 + g;
            WhT[(size_t)j * HH + k0 + tx] = f2b(t[tx][hl]);
        }
        return;
    }
    {
        // proj: pb = bid-4608 in [0,256): g = pb&3, tile = pb>>2, hcol0 = tile*16
        int pb = bid - 4608;
        int g = pb & 3, hcol0 = (pb >> 2) * 16;
        const float* Wx = (g == 0) ? Wfx : (g == 1) ? Wix : (g == 2) ? Wgx : Wox;
        const float* bb = (g == 0) ? bf_ : (g == 1) ? bi_ : (g == 2) ? bg_ : bo_;
        // stage Wx[:, hcol0..+16] into LDS as float4 over d
        for (int i = threadIdx.x; i < 2048; i += 256) {
            int d4 = i >> 4, hc = i & 15;
            const float* w = Wx + (size_t)(d4 * 4) * HH + hcol0 + hc;
            wxs[d4][hc] = make_float4(w[0], w[HH], w[2 * HH], w[3 * HH]);
        }
        __syncthreads();
        int hc = threadIdx.x & 15, c0 = threadIdx.x >> 4;
        float bias = bb[hcol0 + hc];
        for (int c = c0; c < NCLS; c += 16) {
            const float4* er = reinterpret_cast<const float4*>(emb + (size_t)c * DD);
            float acc = bias;
            #pragma unroll 8
            for (int d4 = 0; d4 < 128; d4++) {
                float4 e = er[d4];          // broadcast across the 16-thread group
                float4 w = wxs[d4][hc];
                acc += e.x * w.x + e.y * w.y + e.z * w.z + e.w * w.w;
            }
            proj[(size_t)c * G4 + (hcol0 + hc) * 4 + g] = acc;
        }
    }
}

// ---- L2-bypassing 16B load from rolling base (h is cross-XCD dynamic data)
#define LDAB(d, B, L) asm volatile("global_load_dwordx4 %0, %1, off offset:" L " sc0 sc1" \
                                   : "=v"(d) : "v"(B))
// 4 contiguous 1KB loads then advance base 4KB (13-bit offset limit)
#define LD4(A, I) do { \
    LDAB(A[(I)+0], p, "0"); LDAB(A[(I)+1], p, "1024"); \
    LDAB(A[(I)+2], p, "2048"); LDAB(A[(I)+3], p, "3072"); p += 4096; } while (0)
#define LD16(A) do { LD4(A,0); LD4(A,4); LD4(A,8); LD4(A,12); } while (0)

// ---- waitcnt with data-tie so MFMAs can't be scheduled before the wait
#define WAITA(N, A) asm volatile("s_waitcnt vmcnt(" N ")" : \
    "+v"(A[0]),"+v"(A[1]),"+v"(A[2]),"+v"(A[3]),"+v"(A[4]),"+v"(A[5]),"+v"(A[6]),"+v"(A[7]), \
    "+v"(A[8]),"+v"(A[9]),"+v"(A[10]),"+v"(A[11]),"+v"(A[12]),"+v"(A[13]),"+v"(A[14]),"+v"(A[15]))

#define MF16(A, KB) do { \
    acc0 = __builtin_amdgcn_mfma_f32_32x32x16_bf16(A[0],  breg[(KB)+0],  acc0, 0,0,0); \
    acc1 = __builtin_amdgcn_mfma_f32_32x32x16_bf16(A[1],  breg[(KB)+1],  acc1, 0,0,0); \
    acc0 = __builtin_amdgcn_mfma_f32_32x32x16_bf16(A[2],  breg[(KB)+2],  acc0, 0,0,0); \
    acc1 = __builtin_amdgcn_mfma_f32_32x32x16_bf16(A[3],  breg[(KB)+3],  acc1, 0,0,0); \
    acc0 = __builtin_amdgcn_mfma_f32_32x32x16_bf16(A[4],  breg[(KB)+4],  acc0, 0,0,0); \
    acc1 = __builtin_amdgcn_mfma_f32_32x32x16_bf16(A[5],  breg[(KB)+5],  acc1, 0,0,0); \
    acc0 = __builtin_amdgcn_mfma_f32_32x32x16_bf16(A[6],  breg[(KB)+6],  acc0, 0,0,0); \
    acc1 = __builtin_amdgcn_mfma_f32_32x32x16_bf16(A[7],  breg[(KB)+7],  acc1, 0,0,0); \
    acc0 = __builtin_amdgcn_mfma_f32_32x32x16_bf16(A[8],  breg[(KB)+8],  acc0, 0,0,0); \
    acc1 = __builtin_amdgcn_mfma_f32_32x32x16_bf16(A[9],  breg[(KB)+9],  acc1, 0,0,0); \
    acc0 = __builtin_amdgcn_mfma_f32_32x32x16_bf16(A[10], breg[(KB)+10], acc0, 0,0,0); \
    acc1 = __builtin_amdgcn_mfma_f32_32x32x16_bf16(A[11], breg[(KB)+11], acc1, 0,0,0); \
    acc0 = __builtin_amdgcn_mfma_f32_32x32x16_bf16(A[12], breg[(KB)+12], acc0, 0,0,0); \
    acc1 = __builtin_amdgcn_mfma_f32_32x32x16_bf16(A[13], breg[(KB)+13], acc1, 0,0,0); \
    acc0 = __builtin_amdgcn_mfma_f32_32x32x16_bf16(A[14], breg[(KB)+14], acc0, 0,0,0); \
    acc1 = __builtin_amdgcn_mfma_f32_32x32x16_bf16(A[15], breg[(KB)+15], acc1, 0,0,0); \
} while (0)

// 16 gathered proj loads (normal caching); issued BEFORE the poll (r7 lesson),
// completed by the poll's vmcnt(0).
#define PRLOAD(DSTA, CLSBUF) do { \
    _Pragma("unroll") \
    for (int r = 0; r < 16; r++) { \
        int row = (r & 3) + 8 * (r >> 2) + 4 * half; \
        const float* pa = proj + (size_t)CLSBUF[row] * G4 + jg; \
        asm volatile("global_load_dword %0, %1, off" : "=v"(DSTA[r]) \
                     : "v"((unsigned long long)pa)); \
    } \
} while (0)

// ---------------- persistent LSTM scan (r10 winner, byte-identical) ----------
// 256 WGs x 128 thr (2 waves), waves FULLY DECOUPLED: wave wv of WG(mg,ng)
// owns gate-cols for hcols ng*16+wv*8..+8 end to end. Per-step __syncthreads
// replaced by in-wave s_waitcnt lgkmcnt(0); per-wave clsW buffers.
// ONE-HOP barrier per mg-group, arrivals spread over 8 lines, 128 arrivals
// per group (lane 0 of each wave posts after its own vmcnt(0) drain).
__global__ __launch_bounds__(128, 1)
void k_scan(const int* __restrict__ x, const float* __restrict__ proj,
            const unsigned short* __restrict__ WhT,
            unsigned short* __restrict__ hb0, unsigned short* __restrict__ hb1,
            float* __restrict__ hf32, int* __restrict__ flags) {
    const int wg = blockIdx.x, tid = threadIdx.x;
    const int lane = tid & 63, wv = tid >> 6;
    const int l31 = lane & 31, half = lane >> 5;
    const int mg = wg & 3, ng = wg >> 2;
    const int m0 = mg * 32, n0 = ng * 64;
    const int jg = n0 + wv * 32 + l31;       // this lane's gate-col

    // B fragments: WhT[jg][k], k = kk*16 + half*8 + j  (256 regs)
    short8 breg[64];
    {
        const unsigned short* Bp = WhT + (size_t)jg * HH + half * 8;
        #pragma unroll
        for (int kk = 0; kk < 64; kk++) breg[kk] = ld16(Bp + kk * 16);
    }

    __shared__ float sg[32][68];      // sigmoided gates [row][gate-col]; cols
                                      // 0..31 wave0-private, 32..63 wave1-private
    __shared__ int   clsW[2][2][32];  // per-wave double-buffered class ids

    float Cst[4] = {0.0f, 0.0f, 0.0f, 0.0f};
    const int urow = tid & 31, uq = tid >> 5;   // uq in {2wv, 2wv+1}

    if (lane < 32) clsW[wv][0][lane] = x[(size_t)(m0 + lane) * SS];
    // no barrier: clsW[wv] is wave-private; lgkmcnt(0) below orders it

    // fragment-major bases: hF byte offset = mg*65536 + kk*1024 + lane*16
    const unsigned long long ab0 =
        (unsigned long long)((char*)hb0 + mg * 65536 + lane * 16);
    const unsigned long long ab1 =
        (unsigned long long)((char*)hb1 + mg * 65536 + lane * 16);
    // producer store base: lane_c = urow + 32*(uq>>1), sub = (uq&1)*8 bytes
    const unsigned long long sb0 = (unsigned long long)((char*)hb0 + mg * 65536
        + ng * 1024 + (urow + ((uq >> 1) << 5)) * 16 + (uq & 1) * 8);
    const unsigned long long sb1 = (unsigned long long)((char*)hb1 + mg * 65536
        + ng * 1024 + (urow + ((uq >> 1) << 5)) * 16 + (uq & 1) * 8);

    // 8 arrival lines per mg-group, 128B-strided (zeroed by k_pre):
    // each WAVE adds to line (ng&7); poll reads line (lane&7).
    const unsigned long long ctrAddr =
        (unsigned long long)(flags + (size_t)(8192 + mg * 256 + (ng & 7) * 32));
    const unsigned long long pollAddr =
        (unsigned long long)(flags + (size_t)(8192 + mg * 256 + (lane & 7) * 32));

    float pr[16];
    PRLOAD(pr, clsW[wv][0]);        // step-0 proj gather (drained by first WAITA)

    for (int s = 0; s < SS; s++) {
        const int cur = s & 1;
        unsigned long long p = cur ? ab1 : ab0;
        const unsigned long long sb = cur ? sb0 : sb1;   // store to the OTHER buffer

        // ---- pipelined A loads: 4 groups x 16 x 1KB contiguous ----
        short8 a0[16], a1[16], a2[16], a3[16];
        LD16(a0);
        LD16(a1);

        f32x16 acc0, acc1;
        #pragma unroll
        for (int r = 0; r < 16; r++) { acc0[r] = 0.0f; acc1[r] = 0.0f; }

        WAITA("16", a0);
        LD16(a2);
        MF16(a0, 0);
        WAITA("16", a1);
        LD16(a3);
        MF16(a1, 16);
        WAITA("16", a2);
        MF16(a2, 32);
        WAITA("0", a3);
        MF16(a3, 48);

        // ---- epilogue: add preloaded proj, sigmoid, stash in own sg cols ----
        // C/D layout (m74/m101): col = lane&31, row = (r&3) + 8*(r>>2) + 4*(lane>>5)
        #pragma unroll
        for (int r = 0; r < 16; r++) {
            int row = (r & 3) + 8 * (r >> 2) + 4 * half;
            sg[row][wv * 32 + l31] = sigm(acc0[r] + acc1[r] + pr[r]);
        }
        // in-wave cross-lane handoff: wait LDS writes, no inter-wave barrier
        asm volatile("s_waitcnt lgkmcnt(0)" ::: "memory");

        // ---- pointwise: thread owns (row = tid&31, hcols uq*4..+4) ----
        {
            const float rr = (clsW[wv][cur][urow] > 0) ? 1.0f : 0.0f;
            unsigned short hv[4];
            #pragma unroll
            for (int q = 0; q < 4; q++) {
                float4 gq = *reinterpret_cast<const float4*>(&sg[urow][uq * 16 + q * 4]);
                float cn = (gq.z * gq.y + Cst[q] * gq.x) * rr;   // (g*i + C*f)*r
                Cst[q] = cn;
                float hvv = gq.w * tanh_(cn);
                hv[q] = f2b(hvv);
                if (s == SS - 1)
                    hf32[(size_t)(m0 + urow) * HH + ng * 16 + uq * 4 + q] = hvv;
            }
            unsigned long long pk = (unsigned long long)hv[0]
                                  | ((unsigned long long)hv[1] << 16)
                                  | ((unsigned long long)hv[2] << 32)
                                  | ((unsigned long long)hv[3] << 48);
            asm volatile("global_store_dwordx2 %0, %1, off sc0 sc1" :: "v"(sb), "v"(pk) : "memory");
            if (s + 1 < SS && lane < 32)
                clsW[wv][cur ^ 1][lane] = x[(size_t)(m0 + lane) * SS + s + 1];
        }

        // ---- per-wave barrier leg: drain own h-stores, post arrival, poll ----
        if (s < SS - 1) {
            asm volatile("s_waitcnt vmcnt(0)" ::: "memory");   // own stores at L3
            if (lane == 0) {
                int one = 1;
                asm volatile("global_atomic_add %0, %1, off"
                             :: "v"(ctrAddr), "v"(one) : "memory");
            }
            PRLOAD(pr, clsW[wv][cur ^ 1]); // next step's proj gather, rides the poll
            const int tv = (s + 1) << 4;   // 16 waves per arrival line
            int got;
            do {   // one wide poll: lane l watches line l&7 (single RT/iter)
                asm volatile("global_load_dword %0, %1, off sc0 sc1\n\t"
                             "s_waitcnt vmcnt(0)"
                             : "=v"(got) : "v"(pollAddr) : "memory");
            } while (__ballot(got >= tv) != ~0ull);
        }
    }
}

// ---------------- final projection + log_softmax (k-split 4-way) ----------------
__global__ void k_final(const float* __restrict__ hf32, const float* __restrict__ Wph,
                        const float* __restrict__ bp, float* __restrict__ out) {
    __shared__ float part[512];
    __shared__ float red[128];
    const int b = blockIdx.x, tid = threadIdx.x;
    const int c = tid & 127, q = tid >> 7;     // q: k-quarter 0..3
    const float* hr = hf32 + (size_t)b * HH + q * 256;
    const float* wp = Wph + (size_t)(q * 256) * NCC + c;
    float acc = 0.0f;
    #pragma unroll 8
    for (int k = 0; k < 256; k++) acc += hr[k] * wp[(size_t)k * NCC];
    part[tid] = acc;
    __syncthreads();
    float a = 0.0f;
    if (tid < 128) {
        a = part[c] + part[c + 128] + part[c + 256] + part[c + 384] + bp[c];
        red[c] = a;
    }
    __syncthreads();
    for (int st = 64; st > 0; st >>= 1) {
        if (tid < st) red[tid] = fmaxf(red[tid], red[tid + st]);
        __syncthreads();
    }
    float m = red[0];
    __syncthreads();
    if (tid < 128) red[tid] = __expf(a - m);
    __syncthreads();
    for (int st = 64; st > 0; st >>= 1) {
        if (tid < st) red[tid] += red[tid + st];
        __syncthreads();
    }
    if (tid < 128) out[(size_t)b * NCC + tid] = a - m - __logf(red[0]);
}

extern "C" void kernel_launch(void* const* d_in, const int* in_sizes, int n_in,
                              void* d_out, int out_size, void* d_ws, size_t ws_size,
                              hipStream_t stream) {
    const int*   x   = (const int*)  d_in[0];
    const float* emb = (const float*)d_in[1];
    const float* Wfx = (const float*)d_in[2];
    const float* Wfh = (const float*)d_in[3];
    const float* bf_ = (const float*)d_in[4];
    const float* Wix = (const float*)d_in[5];
    const float* Wih = (const float*)d_in[6];
    const float* bi_ = (const float*)d_in[7];
    const float* Wgx = (const float*)d_in[8];
    const float* Wgh = (const float*)d_in[9];
    const float* bg_ = (const float*)d_in[10];
    const float* Wox = (const float*)d_in[11];
    const float* Woh = (const float*)d_in[12];
    const float* bo_ = (const float*)d_in[13];
    const float* Wph = (const float*)d_in[14];
    const float* bp_ = (const float*)d_in[15];
    float* out = (float*)d_out;

    char* ws = (char*)d_ws;
    unsigned short* WhT   = (unsigned short*)(ws);              // 8 MB
    float*          proj  = (float*)(ws + 8388608);             // 2.02 MB -> ends 10502144
    int*            flags = (int*)(ws + 10502656);              // 64 KB (16384 ints)
    unsigned short* hb0   = (unsigned short*)(ws + 10568192);   // 256 KB
    unsigned short* hb1   = (unsigned short*)(ws + 10830336);   // 256 KB
    float*          hf32  = (float*)(ws + 11092480);            // 512 KB -> ends ~11.6 MB

    k_pre<<<dim3(4864), dim3(256), 0, stream>>>(hb0, flags, Wfh, Wih, Wgh, Woh, WhT,
                                                emb, Wfx, Wix, Wgx, Wox,
                                                bf_, bi_, bg_, bo_, proj);
    k_scan<<<dim3(NWG), dim3(128), 0, stream>>>(x, proj, WhT, hb0, hb1, hf32, flags);
    k_final<<<dim3(128), dim3(512), 0, stream>>>(hf32, Wph, bp_, out);
}